// Round 1
// baseline (679.318 us; speedup 1.0000x reference)
//
#include <hip/hip_runtime.h>

#define D 64
#define NNODES 100000
#define NGRAPHS 128

// ---------------- zero buffer (float4 grid-stride) ----------------
__global__ void zero_kernel(float* __restrict__ buf, int n4) {
    int i = blockIdx.x * blockDim.x + threadIdx.x;
    int stride = gridDim.x * blockDim.x;
    float4 z = make_float4(0.f, 0.f, 0.f, 0.f);
    for (; i < n4; i += stride) ((float4*)buf)[i] = z;
}

// ---------------- edge scatter: agg[dst] += x[src] ----------------
// thread g: edge e = g>>6, feature d = g&63. 64 lanes of a wave share one
// edge -> src/dst loads broadcast, x row read is one coalesced 256B segment.
__global__ void scatter_kernel(const float* __restrict__ x,
                               const int* __restrict__ src,
                               const int* __restrict__ dst,
                               float* __restrict__ agg, int nE) {
    long long g = (long long)blockIdx.x * blockDim.x + threadIdx.x;
    int e = (int)(g >> 6);
    if (e >= nE) return;
    int d = (int)(g & 63);
    int s = src[e];
    int t = dst[e];
    float v = x[(long long)s * D + d];
    atomicAdd(&agg[(long long)t * D + d], v);
}

// ---------------- fused (x + agg) @ W + b [, relu] ----------------
// W staged in LDS (16KB). One wave per node: lane k writes xs[k], then each
// lane d accumulates sum_k xs[k]*Ws[k*64+d]. xs[k] is a broadcast read (free),
// Ws read is a 2-way bank alias (free on CDNA4).
template <bool RELU>
__global__ void mlp_kernel(const float* __restrict__ x,
                           const float* __restrict__ agg,
                           const float* __restrict__ W,
                           const float* __restrict__ b,
                           float* __restrict__ out, int n) {
    __shared__ float Ws[D * D];
    __shared__ float bs[D];
    __shared__ float xs[4][D];
    int tid = threadIdx.x;
    for (int i = tid; i < D * D / 4; i += blockDim.x)
        ((float4*)Ws)[i] = ((const float4*)W)[i];
    if (tid < D) bs[tid] = b[tid];
    __syncthreads();

    int w = tid >> 6, lane = tid & 63;
    int node = blockIdx.x * 4 + w;
    int stride = gridDim.x * 4;
    for (; node < n; node += stride) {
        xs[w][lane] = x[(long long)node * D + lane] + agg[(long long)node * D + lane];
        float acc = bs[lane];
#pragma unroll
        for (int k = 0; k < D; ++k)
            acc = fmaf(xs[w][k], Ws[k * D + lane], acc);
        out[(long long)node * D + lane] = RELU ? fmaxf(acc, 0.f) : acc;
    }
}

// ------- final layer fused with sorted-segment sum pooling -------
// Each wave owns a contiguous node range; graph_id is sorted, so we
// accumulate in registers and flush one atomicAdd per segment change.
__global__ void mlp_pool_kernel(const float* __restrict__ x,
                                const float* __restrict__ agg,
                                const float* __restrict__ W,
                                const float* __restrict__ b,
                                const int* __restrict__ gid,
                                float* __restrict__ out, int n) {
    __shared__ float Ws[D * D];
    __shared__ float bs[D];
    __shared__ float xs[4][D];
    int tid = threadIdx.x;
    for (int i = tid; i < D * D / 4; i += blockDim.x)
        ((float4*)Ws)[i] = ((const float4*)W)[i];
    if (tid < D) bs[tid] = b[tid];
    __syncthreads();

    int w = tid >> 6, lane = tid & 63;
    int waves_total = gridDim.x * 4;
    int wave_id = blockIdx.x * 4 + w;
    int chunk = (n + waves_total - 1) / waves_total;
    int start = wave_id * chunk;
    int end = min(start + chunk, n);

    float accp = 0.f;
    int cur = -1;
    for (int node = start; node < end; ++node) {
        xs[w][lane] = x[(long long)node * D + lane] + agg[(long long)node * D + lane];
        float acc = bs[lane];
#pragma unroll
        for (int k = 0; k < D; ++k)
            acc = fmaf(xs[w][k], Ws[k * D + lane], acc);
        int g = gid[node];           // uniform across the wave
        if (g != cur) {
            if (cur >= 0) atomicAdd(&out[cur * D + lane], accp);
            cur = g;
            accp = 0.f;
        }
        accp += acc;
    }
    if (cur >= 0) atomicAdd(&out[cur * D + lane], accp);
}

extern "C" void kernel_launch(void* const* d_in, const int* in_sizes, int n_in,
                              void* d_out, int out_size, void* d_ws, size_t ws_size,
                              hipStream_t stream) {
    const float* feats = (const float*)d_in[0];
    const int*   src   = (const int*)d_in[1];
    const int*   dst   = (const int*)d_in[2];
    const int*   gid   = (const int*)d_in[3];
    const float* W1    = (const float*)d_in[4];
    const float* b1    = (const float*)d_in[5];
    const float* W2    = (const float*)d_in[6];
    const float* b2    = (const float*)d_in[7];
    float* out = (float*)d_out;

    float* agg = (float*)d_ws;                       // NNODES*D floats
    float* h   = agg + (size_t)NNODES * D;           // NNODES*D floats

    int nE = in_sizes[1];
    int nScatterBlocks = (int)(((long long)nE * 64 + 255) / 256);

    // layer 1
    zero_kernel<<<2048, 256, 0, stream>>>(agg, NNODES * D / 4);
    scatter_kernel<<<nScatterBlocks, 256, 0, stream>>>(feats, src, dst, agg, nE);
    mlp_kernel<true><<<2048, 256, 0, stream>>>(feats, agg, W1, b1, h, NNODES);

    // layer 2
    zero_kernel<<<2048, 256, 0, stream>>>(agg, NNODES * D / 4);
    scatter_kernel<<<nScatterBlocks, 256, 0, stream>>>(h, src, dst, agg, nE);

    // pooling output
    zero_kernel<<<64, 256, 0, stream>>>(out, NGRAPHS * D / 4);
    mlp_pool_kernel<<<512, 256, 0, stream>>>(h, agg, W2, b2, gid, out, NNODES);
}